// Round 1
// baseline (1453.183 us; speedup 1.0000x reference)
//
#include <hip/hip_runtime.h>
#include <stdint.h>

#define NDATA 200000
#define BATCH 256
#define BITD  64
#define TOPF  20
#define KNEG  2500
#define RANKA 20000            // N_DATA - HIGH
#define TVAL  7.2f
#define S8T   (8.0f/7.2f)
#define THRV  0.3f
#define TAU   0.976f

#define NB    512
#define HLO   (-0.35f)
#define HINV  1024.0f          // NB / 0.5 range

#define CF    4096             // fnp candidate cap (sims > 0.3); also sort size
#define CN    6144             // neg candidate cap (keys > TAU); sort size 8192

#define SBS   64               // samples per block in main pass
#define NSB   4                // sample blocks
#define CHUNK 3200
#define NCH   63               // 63*3200 = 201600 >= 200000
#define RT    128              // rows per tile
#define NTILE 25               // 25*128 = 3200

__device__ __forceinline__ int binOf(float sim) {
    int b = (int)floorf((sim - HLO) * HINV);
    b = b < 0 ? 0 : b;
    b = b > (NB - 1) ? (NB - 1) : b;
    return b;
}

// ---------------------------------------------------------------- kernel A
__global__ __launch_bounds__(64) void k_prep(
    const float* __restrict__ iA, const float* __restrict__ iB,
    const float* __restrict__ tA, const float* __restrict__ tB,
    const float* __restrict__ mem, const int* __restrict__ bidx,
    float* __restrict__ fsum_g, float* __restrict__ f1_g,
    float* __restrict__ upd_g, float* __restrict__ posExp_g,
    unsigned* __restrict__ fnpCnt, unsigned* __restrict__ negCnt,
    unsigned* __restrict__ hist_g, float* __restrict__ losses)
{
    int s = blockIdx.x, j = threadIdx.x;
    float a = iA[s * BITD + j], b = iB[s * BITD + j];
    float c = tA[s * BITD + j], d = tB[s * BITD + j];
    float f1 = 0.5f * (a + c), f2 = 0.5f * (a + d);
    float f3 = 0.5f * (b + c), f4 = 0.5f * (b + d);
    float q1 = f1 * f1, q2 = f2 * f2, q3 = f3 * f3, q4 = f4 * f4;
#pragma unroll
    for (int m = 1; m < 64; m <<= 1) {
        q1 += __shfl_xor(q1, m); q2 += __shfl_xor(q2, m);
        q3 += __shfl_xor(q3, m); q4 += __shfl_xor(q4, m);
    }
    float n1 = sqrtf(q1), n2 = sqrtf(q2), n3 = sqrtf(q3), n4 = sqrtf(q4);
    float fs = 0.25f * (f1 / n1 + f2 / n2 + f3 / n3 + f4 / n4);
    fsum_g[s * BITD + j] = fs;
    f1_g[s * BITD + j] = f1;

    int pos = bidx[s];
    float mv = mem[(size_t)pos * BITD + j];
    float sg = (mv > 0.f) ? 1.f : ((mv < 0.f) ? -1.f : 0.f);
    float ps = sg * f1;
#pragma unroll
    for (int m = 1; m < 64; m <<= 1) ps += __shfl_xor(ps, m);

    float nf = f1 / n1;
    float u = mv * 0.4f + nf * 0.6f;
    float uq = u * u;
#pragma unroll
    for (int m = 1; m < 64; m <<= 1) uq += __shfl_xor(uq, m);
    upd_g[s * BITD + j] = u / sqrtf(uq);

    if (j == 0) {
        posExp_g[s] = expf(ps / TVAL);
        fnpCnt[s] = 0u; negCnt[s] = 0u; losses[s] = 0.f;
    }
    for (int k = j; k < NB; k += 64) hist_g[(size_t)s * NB + k] = 0u;
}

// ---------------------------------------------------------------- kernel B
__global__ __launch_bounds__(256) void k_main(
    const float* __restrict__ mem, const float* __restrict__ ru,
    const float* __restrict__ fsum_g, const float* __restrict__ f1_g,
    unsigned* __restrict__ fnpCnt, unsigned* __restrict__ negCnt,
    float* __restrict__ fnpSim, int* __restrict__ fnpIdx, float* __restrict__ fnpE,
    float* __restrict__ negKey, int* __restrict__ negIdx,
    float* __restrict__ negSim, float* __restrict__ negE,
    unsigned* __restrict__ hist_g)
{
    __shared__ float fsumT[BITD * 65];          // [j][s]
    __shared__ float f1L[SBS * 68];             // [s][j]
    __shared__ float rowT[BITD * 132];          // [j][r swizzled]
    __shared__ unsigned histL[(SBS / 2) * NB];  // packed u16 pairs
    __shared__ unsigned tCnt;
    __shared__ unsigned ePack[1024];
    __shared__ float eSim[1024];
    __shared__ float eKey[1024];

    const int tid = threadIdx.x;
    const int sG = tid & 7;        // sample group 0..7
    const int rG = tid >> 3;       // row group 0..31
    const int sbBase = blockIdx.y * SBS;
    const int chunkBase = blockIdx.x * CHUNK;

    // stage fsumT (transposed) and f1L (row-major)
    for (int q = tid; q < SBS * 16; q += 256) {
        int s = q >> 4, j4 = q & 15;
        float4 v = *(const float4*)&fsum_g[(size_t)(sbBase + s) * BITD + j4 * 4];
        fsumT[(4 * j4 + 0) * 65 + s] = v.x;
        fsumT[(4 * j4 + 1) * 65 + s] = v.y;
        fsumT[(4 * j4 + 2) * 65 + s] = v.z;
        fsumT[(4 * j4 + 3) * 65 + s] = v.w;
        float4 w = *(const float4*)&f1_g[(size_t)(sbBase + s) * BITD + j4 * 4];
        *(float4*)&f1L[s * 68 + j4 * 4] = w;
    }
    for (int q = tid; q < (SBS / 2) * NB; q += 256) histL[q] = 0u;
    if (tid == 0) tCnt = 0u;

    for (int t2 = 0; t2 < NTILE; ++t2) {
        int rowBase = chunkBase + t2 * RT;
        // stage row tile (transposed + XOR swizzle on r by (j>>2)&7)
        for (int q = tid; q < RT * 16; q += 256) {
            int r = q >> 4, j4 = q & 15;
            int g = rowBase + r;
            float4 v = make_float4(0.f, 0.f, 0.f, 0.f);
            if (g < NDATA) v = *(const float4*)&mem[(size_t)g * BITD + j4 * 4];
            int swz = (j4 & 7) << 2;
            rowT[(4 * j4 + 0) * 132 + (r ^ swz)] = v.x;
            rowT[(4 * j4 + 1) * 132 + (r ^ swz)] = v.y;
            rowT[(4 * j4 + 2) * 132 + (r ^ swz)] = v.z;
            rowT[(4 * j4 + 3) * 132 + (r ^ swz)] = v.w;
        }
        __syncthreads();

        float acc[8][4];
#pragma unroll
        for (int i = 0; i < 8; ++i)
#pragma unroll
            for (int c2 = 0; c2 < 4; ++c2) acc[i][c2] = 0.f;

#pragma unroll 4
        for (int j = 0; j < BITD; ++j) {
            const float4 rv = *(const float4*)&rowT[j * 132 + ((4 * rG) ^ (((j >> 2) & 7) << 2))];
            const float4 fa = *(const float4*)&fsumT[j * 65 + 8 * sG];
            const float4 fb = *(const float4*)&fsumT[j * 65 + 8 * sG + 4];
            const float fsv[8] = {fa.x, fa.y, fa.z, fa.w, fb.x, fb.y, fb.z, fb.w};
            const float rvv[4] = {rv.x, rv.y, rv.z, rv.w};
#pragma unroll
            for (int i = 0; i < 8; ++i)
#pragma unroll
                for (int c2 = 0; c2 < 4; ++c2)
                    acc[i][c2] = fmaf(fsv[i], rvv[c2], acc[i][c2]);
        }

        // output phase
        int rb = rowBase + 4 * rG;
        if (rb < NDATA) {
            float4 kvs[8];
#pragma unroll
            for (int i = 0; i < 8; ++i) {
                int sg2 = sbBase + 8 * sG + i;
                kvs[i] = *(const float4*)&ru[(size_t)sg2 * NDATA + rb];
            }
#pragma unroll
            for (int i = 0; i < 8; ++i) {
                int s = 8 * sG + i;
                const float kk[4] = {kvs[i].x, kvs[i].y, kvs[i].z, kvs[i].w};
#pragma unroll
                for (int c2 = 0; c2 < 4; ++c2) {
                    float sim = acc[i][c2];
                    int bin = binOf(sim);
                    atomicAdd(&histL[(s >> 1) * NB + bin], 1u << ((s & 1) * 16));
                    bool isF = sim > THRV;
                    bool isN = kk[c2] > TAU;
                    if (isF || isN) {
                        unsigned sl = atomicAdd(&tCnt, 1u);
                        if (sl < 1024u) {
                            ePack[sl] = (unsigned)s | ((unsigned)(4 * rG + c2) << 6) |
                                        (isF ? (1u << 13) : 0u) | (isN ? (1u << 14) : 0u);
                            eSim[sl] = sim;
                            eKey[sl] = kk[c2];
                        }
                    }
                }
            }
        }
        __syncthreads();

        // deferred e = f1 . mem_row for appended entries (4 lanes per entry)
        unsigned E = tCnt; if (E > 1024u) E = 1024u;
        int grp = tid >> 2, lp = tid & 3;
        for (unsigned e2 = grp; e2 < E; e2 += 64) {
            unsigned pk = ePack[e2];
            int s = pk & 63;
            int rl = (pk >> 6) & 127;
            int g = rowBase + rl;
            int sg2 = sbBase + s;
            const float4* mrow = (const float4*)&mem[(size_t)g * BITD + lp * 16];
            const float4* frow = (const float4*)&f1L[s * 68 + lp * 16];
            float part = 0.f;
#pragma unroll
            for (int m = 0; m < 4; ++m) {
                float4 mv = mrow[m];
                float4 fv = frow[m];
                part += mv.x * fv.x + mv.y * fv.y + mv.z * fv.z + mv.w * fv.w;
            }
            part += __shfl_xor(part, 1);
            part += __shfl_xor(part, 2);
            if (lp == 0) {
                float sim = eSim[e2], key = eKey[e2];
                if (pk & (1u << 13)) {
                    unsigned sl = atomicAdd(&fnpCnt[sg2], 1u);
                    if (sl < CF) {
                        fnpSim[(size_t)sg2 * CF + sl] = sim;
                        fnpIdx[(size_t)sg2 * CF + sl] = g;
                        fnpE[(size_t)sg2 * CF + sl] = part;
                    }
                }
                if (pk & (1u << 14)) {
                    unsigned sl = atomicAdd(&negCnt[sg2], 1u);
                    if (sl < CN) {
                        negKey[(size_t)sg2 * CN + sl] = key;
                        negIdx[(size_t)sg2 * CN + sl] = g;
                        negSim[(size_t)sg2 * CN + sl] = sim;
                        negE[(size_t)sg2 * CN + sl] = part;
                    }
                }
            }
        }
        __syncthreads();
        if (tid == 0) tCnt = 0u;
        // next iteration's first __syncthreads() makes the reset visible
    }

    __syncthreads();
    // merge histograms
    for (int q = tid; q < SBS * NB; q += 256) {
        int s = q >> 9;
        int bin = q & (NB - 1);
        unsigned w2 = histL[(s >> 1) * NB + bin];
        unsigned c2 = (w2 >> ((s & 1) * 16)) & 0xffffu;
        if (c2) atomicAdd(&hist_g[(size_t)(sbBase + s) * NB + bin], c2);
    }
}

// ---------------------------------------------------------------- kernel C
__device__ void bitonic_desc(uint64_t* arr, int M) {
    int tid = threadIdx.x;
    for (int k = 2; k <= M; k <<= 1) {
        for (int j2 = k >> 1; j2 > 0; j2 >>= 1) {
            __syncthreads();
            for (int i2 = tid; i2 < M; i2 += 256) {
                int ixj = i2 ^ j2;
                if (ixj > i2) {
                    uint64_t a = arr[i2], b = arr[ixj];
                    bool dsc = ((i2 & k) == 0);
                    if ((a < b) == dsc) { arr[i2] = b; arr[ixj] = a; }
                }
            }
        }
    }
    __syncthreads();
}

__global__ __launch_bounds__(256) void k_fin(
    const int* __restrict__ bidx,
    const unsigned* __restrict__ fnpCnt, const unsigned* __restrict__ negCnt,
    const float* __restrict__ fnpSim, const int* __restrict__ fnpIdx,
    const float* __restrict__ fnpE,
    const float* __restrict__ negKey, const int* __restrict__ negIdx,
    const float* __restrict__ negSim, const float* __restrict__ negE,
    const unsigned* __restrict__ hist_g, const float* __restrict__ posExp_g,
    float* __restrict__ losses)
{
    __shared__ uint64_t arr[8192];
    __shared__ unsigned tot[256];
    __shared__ int shI[2];
    __shared__ float shNum[1];
    __shared__ int exclIdx[24];
    __shared__ float wsum[4];

    int s = blockIdx.x, tid = threadIdx.x;
    int pos = bidx[s];

    if (tid == 0) {
        unsigned cum = 0; int beta = NB - 1;
        for (int b2 = 0; b2 < NB; ++b2) {
            cum += hist_g[(size_t)s * NB + b2];
            if (cum >= (unsigned)(RANKA + 1)) { beta = b2; break; }
        }
        shI[0] = beta;
    }

    // ---- fnp phase
    unsigned cf = fnpCnt[s]; if (cf > CF) cf = CF;
    for (int i2 = tid; i2 < CF; i2 += 256) {
        uint64_t v = 0;
        if (i2 < (int)cf) {
            unsigned sb2 = __float_as_uint(fnpSim[(size_t)s * CF + i2]);
            unsigned pk = ((unsigned)fnpIdx[(size_t)s * CF + i2] << 13) | (unsigned)i2;
            v = ((uint64_t)sb2 << 32) | (uint64_t)(unsigned)(~pk);
        }
        arr[i2] = v;
    }
    bitonic_desc(arr, CF);
    if (tid == 0) {
        float numer = posExp_g[s];
        int ne = 0;
        int lim = (int)cf; if (lim > TOPF) lim = TOPF;
        for (int i2 = 0; i2 < lim; ++i2) {
            unsigned pk = ~(unsigned)(arr[i2] & 0xffffffffull);
            int ix = (int)(pk >> 13);
            int sl = (int)(pk & 8191u);
            if (ix != pos) {
                float ev = fnpE[(size_t)s * CF + sl];
                float fsim = ev * S8T;
                numer += fsim * expf(fsim);
                exclIdx[ne++] = ix;
            }
        }
        shNum[0] = numer; shI[1] = ne;
    }
    __syncthreads();
    int beta = shI[0], nE = shI[1];

    // ---- neg phase
    unsigned cn = negCnt[s]; if (cn > CN) cn = CN;
    for (int i2 = tid; i2 < 8192; i2 += 256) {
        uint64_t v = 0;
        if (i2 < (int)cn) {
            unsigned kb = __float_as_uint(negKey[(size_t)s * CN + i2]);
            unsigned pk = ((unsigned)negIdx[(size_t)s * CN + i2] << 13) | (unsigned)i2;
            v = ((uint64_t)kb << 32) | (uint64_t)(unsigned)(~pk);
        }
        arr[i2] = v;
    }
    bitonic_desc(arr, 8192);

    unsigned pl = 0;
    int base2 = tid * 32;
    unsigned cnt2 = 0;
#pragma unroll
    for (int k2 = 0; k2 < 32; ++k2) {
        unsigned p = 0;
        uint64_t v = arr[base2 + k2];
        if (v) {
            unsigned pk = ~(unsigned)(v & 0xffffffffull);
            int ix = (int)(pk >> 13);
            if (ix != pos) {
                int sl = (int)(pk & 8191u);
                float sm = negSim[(size_t)s * CN + sl];
                if (binOf(sm) >= beta) {
                    bool ex = false;
                    for (int q2 = 0; q2 < nE; ++q2) ex = ex || (exclIdx[q2] == ix);
                    if (!ex) p = 1;
                }
            }
        }
        pl |= p << k2;
        cnt2 += p;
    }
    tot[tid] = cnt2;
    __syncthreads();
    if (tid == 0) {
        unsigned run = 0;
        for (int q2 = 0; q2 < 256; ++q2) { unsigned t3 = tot[q2]; tot[q2] = run; run += t3; }
    }
    __syncthreads();
    unsigned off2 = tot[tid];
    float dsum = 0.f;
#pragma unroll
    for (int k2 = 0; k2 < 32; ++k2) {
        if ((pl >> k2) & 1u) {
            off2 += 1;
            if (off2 <= (unsigned)KNEG) {
                uint64_t v = arr[base2 + k2];
                unsigned pk = ~(unsigned)(v & 0xffffffffull);
                int sl = (int)(pk & 8191u);
                dsum += expf(negE[(size_t)s * CN + sl] * S8T);
            }
        }
    }
#pragma unroll
    for (int m = 1; m < 64; m <<= 1) dsum += __shfl_xor(dsum, m);
    if ((tid & 63) == 0) wsum[tid >> 6] = dsum;
    __syncthreads();
    if (tid == 0) {
        float D = wsum[0] + wsum[1] + wsum[2] + wsum[3] + posExp_g[s];
        losses[s] = -logf(shNum[0] / D) / (1.0f + (float)nE);
    }
}

// ---------------------------------------------------------------- small kernels
__global__ __launch_bounds__(256) void k_loss(const float* __restrict__ losses,
                                              float* __restrict__ out)
{
    __shared__ float buf[256];
    int t = threadIdx.x;
    buf[t] = losses[t];
    __syncthreads();
    for (int st = 128; st > 0; st >>= 1) {
        if (t < st) buf[t] += buf[t + st];
        __syncthreads();
    }
    if (t == 0) out[0] = buf[0] / 256.0f;
}

__global__ __launch_bounds__(256) void k_copy(const float* __restrict__ mem,
                                              float* __restrict__ out)
{
    size_t i = ((size_t)blockIdx.x * 256 + threadIdx.x) * 4;
    if (i < (size_t)NDATA * BITD) {
        float4 v = *(const float4*)&mem[i];
        out[1 + i] = v.x; out[2 + i] = v.y; out[3 + i] = v.z; out[4 + i] = v.w;
    }
}

__global__ __launch_bounds__(64) void k_scatter(const int* __restrict__ bidx,
                                                const float* __restrict__ upd,
                                                float* __restrict__ out)
{
    int s = blockIdx.x, j = threadIdx.x;
    int pos = bidx[s];
    bool last = true;
    for (int s2 = s + 1; s2 < BATCH; ++s2)
        if (bidx[s2] == pos) last = false;   // last write wins (np semantics)
    if (last) out[1 + (size_t)pos * BITD + j] = upd[s * BITD + j];
}

// ---------------------------------------------------------------- launcher
extern "C" void kernel_launch(void* const* d_in, const int* in_sizes, int n_in,
                              void* d_out, int out_size, void* d_ws, size_t ws_size,
                              hipStream_t stream)
{
    const float* iA = (const float*)d_in[0];
    const float* iB = (const float*)d_in[1];
    const float* tA = (const float*)d_in[2];
    const float* tB = (const float*)d_in[3];
    const float* mem = (const float*)d_in[4];
    const float* ru  = (const float*)d_in[5];
    const int* bidx  = (const int*)d_in[6];
    float* out = (float*)d_out;

    char* w = (char*)d_ws;
    float* fsum_g = (float*)w;      w += BATCH * BITD * 4;
    float* f1_g = (float*)w;        w += BATCH * BITD * 4;
    float* upd_g = (float*)w;       w += BATCH * BITD * 4;
    float* posExp_g = (float*)w;    w += BATCH * 4;
    float* losses = (float*)w;      w += BATCH * 4;
    unsigned* fnpCnt = (unsigned*)w; w += BATCH * 4;
    unsigned* negCnt = (unsigned*)w; w += BATCH * 4;
    unsigned* hist_g = (unsigned*)w; w += (size_t)BATCH * NB * 4;
    float* fnpSim = (float*)w;      w += (size_t)BATCH * CF * 4;
    int* fnpIdx = (int*)w;          w += (size_t)BATCH * CF * 4;
    float* fnpE = (float*)w;        w += (size_t)BATCH * CF * 4;
    float* negKey = (float*)w;      w += (size_t)BATCH * CN * 4;
    int* negIdx = (int*)w;          w += (size_t)BATCH * CN * 4;
    float* negSim = (float*)w;      w += (size_t)BATCH * CN * 4;
    float* negE = (float*)w;        w += (size_t)BATCH * CN * 4;

    k_prep<<<BATCH, 64, 0, stream>>>(iA, iB, tA, tB, mem, bidx, fsum_g, f1_g,
                                     upd_g, posExp_g, fnpCnt, negCnt, hist_g, losses);
    k_copy<<<(NDATA * BITD) / 4 / 256, 256, 0, stream>>>(mem, out);
    k_main<<<dim3(NCH, NSB), 256, 0, stream>>>(mem, ru, fsum_g, f1_g,
                                               fnpCnt, negCnt,
                                               fnpSim, fnpIdx, fnpE,
                                               negKey, negIdx, negSim, negE, hist_g);
    k_fin<<<BATCH, 256, 0, stream>>>(bidx, fnpCnt, negCnt,
                                     fnpSim, fnpIdx, fnpE,
                                     negKey, negIdx, negSim, negE,
                                     hist_g, posExp_g, losses);
    k_loss<<<1, 256, 0, stream>>>(losses, out);
    k_scatter<<<BATCH, 64, 0, stream>>>(bidx, upd_g, out);
}

// Round 2
// 1322.454 us; speedup vs baseline: 1.0989x; 1.0989x over previous
//
#include <hip/hip_runtime.h>
#include <stdint.h>

#define NDATA 200000
#define BATCH 256
#define BITD  64
#define TOPF  20
#define KNEG  2500
#define RANKA 20000            // N_DATA - HIGH
#define TVAL  7.2f
#define S8T   (8.0f/7.2f)
#define THRV  0.3f
#define TAU   0.976f
#define KHINV 42666.666f       // 1024/(1-TAU)

#define NB    512
#define HLO   (-0.35f)
#define HINV  1024.0f

#define CF    2048             // fnp candidate cap (sim > 0.3)
#define CN    6144             // neg candidate cap (key > TAU)

#define WCH   16               // tiles (128 rows) per WG
#define NCH   98               // 98*2048 = 200704 >= 200000
#define NSB   8                // sample blocks of 32

typedef unsigned long long u64;
typedef __attribute__((ext_vector_type(16))) float f32x16;
typedef __attribute__((ext_vector_type(8))) short s16x8;

__device__ __forceinline__ int binOf(float sim) {
    int b = (int)floorf((sim - HLO) * HINV);
    b = b < 0 ? 0 : b;
    b = b > (NB - 1) ? (NB - 1) : b;
    return b;
}
__device__ __forceinline__ unsigned short bf16_rne(float x) {
    unsigned u = __float_as_uint(x);
    unsigned r = (u + 0x7FFFu + ((u >> 16) & 1u)) >> 16;
    return (unsigned short)r;
}

// ---------------------------------------------------------------- kernel A
__global__ __launch_bounds__(64) void k_prep(
    const float* __restrict__ iA, const float* __restrict__ iB,
    const float* __restrict__ tA, const float* __restrict__ tB,
    const float* __restrict__ mem, const int* __restrict__ bidx,
    unsigned short* __restrict__ fsumHi, unsigned short* __restrict__ fsumLo,
    float* __restrict__ f1_g, float* __restrict__ upd_g,
    float* __restrict__ posExp_g,
    unsigned* __restrict__ fnpCnt, unsigned* __restrict__ negCnt,
    unsigned* __restrict__ hist_g)
{
    int s = blockIdx.x, j = threadIdx.x;
    float a = iA[s * BITD + j], b = iB[s * BITD + j];
    float c = tA[s * BITD + j], d = tB[s * BITD + j];
    float f1 = 0.5f * (a + c), f2 = 0.5f * (a + d);
    float f3 = 0.5f * (b + c), f4 = 0.5f * (b + d);
    float q1 = f1 * f1, q2 = f2 * f2, q3 = f3 * f3, q4 = f4 * f4;
#pragma unroll
    for (int m = 1; m < 64; m <<= 1) {
        q1 += __shfl_xor(q1, m); q2 += __shfl_xor(q2, m);
        q3 += __shfl_xor(q3, m); q4 += __shfl_xor(q4, m);
    }
    float n1 = sqrtf(q1), n2 = sqrtf(q2), n3 = sqrtf(q3), n4 = sqrtf(q4);
    float fs = 0.25f * (f1 / n1 + f2 / n2 + f3 / n3 + f4 / n4);

    unsigned short hi = bf16_rne(fs);
    float hif = __uint_as_float(((unsigned)hi) << 16);
    unsigned short lo = bf16_rne(fs - hif);
    fsumHi[s * BITD + j] = hi;
    fsumLo[s * BITD + j] = lo;
    f1_g[s * BITD + j] = f1;

    int pos = bidx[s];
    float mv = mem[(size_t)pos * BITD + j];
    float sg = (mv > 0.f) ? 1.f : ((mv < 0.f) ? -1.f : 0.f);
    float ps = sg * f1;
#pragma unroll
    for (int m = 1; m < 64; m <<= 1) ps += __shfl_xor(ps, m);

    float nf = f1 / n1;
    float u = mv * 0.4f + nf * 0.6f;
    float uq = u * u;
#pragma unroll
    for (int m = 1; m < 64; m <<= 1) uq += __shfl_xor(uq, m);
    upd_g[s * BITD + j] = u / sqrtf(uq);

    if (j == 0) {
        posExp_g[s] = expf(ps / TVAL);
        fnpCnt[s] = 0u; negCnt[s] = 0u;
    }
    for (int k = j; k < NB; k += 64) hist_g[(size_t)s * NB + k] = 0u;
}

// ---------------------------------------------------------------- kernel B (MFMA main pass)
__global__ __launch_bounds__(256) void k_main(
    const float* __restrict__ mem, const float* __restrict__ ru,
    const unsigned short* __restrict__ fsumHi, const unsigned short* __restrict__ fsumLo,
    unsigned* __restrict__ fnpCnt, unsigned* __restrict__ negCnt,
    u64* __restrict__ fnpPack, u64* __restrict__ negPack,
    unsigned* __restrict__ hist_g)
{
    __shared__ unsigned histL[4096];   // [bin*8 + (sl>>2)], u8 per sample lane

    const int tid = threadIdx.x;
    const int w = tid >> 6, l = tid & 63;
    const int h = l >> 5, sl = l & 31;
    const int sbBase = blockIdx.y * 32;
    const int sg = sbBase + sl;

    for (int q = tid; q < 4096; q += 256) histL[q] = 0u;
    __syncthreads();

    // B fragments (fsum hi/lo), kept in registers for the whole kernel.
    // 32x32x16 bf16 B-layout: lane l holds B[k = 8*(l>>5)+e][col = l&31]
    s16x8 bHi[4], bLo[4];
    {
        const unsigned short* ph = fsumHi + (size_t)sg * BITD + 8 * h;
        const unsigned short* pl = fsumLo + (size_t)sg * BITD + 8 * h;
#pragma unroll
        for (int ks = 0; ks < 4; ++ks) {
            bHi[ks] = *(const s16x8*)(ph + ks * 16);
            bLo[ks] = *(const s16x8*)(pl + ks * 16);
        }
    }
    const float* rup = ru + (size_t)sg * NDATA;
    const int chunkBase = blockIdx.x * (WCH * 128);

    for (int t = 0; t < WCH; ++t) {
        const int waveRow = chunkBase + t * 128 + 32 * w;
        if (waveRow >= NDATA) continue;   // NDATA is 32-aligned: all-or-nothing per wave

        // A fragments: mem rows, exactly +-0.125 -> bf16 exact
        const float* rp = mem + (size_t)(waveRow + sl) * BITD + 8 * h;
        f32x16 acc;
#pragma unroll
        for (int i = 0; i < 16; ++i) acc[i] = 0.f;
#pragma unroll
        for (int ks = 0; ks < 4; ++ks) {
            float4 p0 = *(const float4*)(rp + ks * 16);
            float4 p1 = *(const float4*)(rp + ks * 16 + 4);
            s16x8 af;
            af[0] = (short)bf16_rne(p0.x); af[1] = (short)bf16_rne(p0.y);
            af[2] = (short)bf16_rne(p0.z); af[3] = (short)bf16_rne(p0.w);
            af[4] = (short)bf16_rne(p1.x); af[5] = (short)bf16_rne(p1.y);
            af[6] = (short)bf16_rne(p1.z); af[7] = (short)bf16_rne(p1.w);
            acc = __builtin_amdgcn_mfma_f32_32x32x16_bf16(af, bHi[ks], acc, 0, 0, 0);
            acc = __builtin_amdgcn_mfma_f32_32x32x16_bf16(af, bLo[ks], acc, 0, 0, 0);
        }

        // keys for this lane's 16 cells: rows r0 + {0..3,8..11,16..19,24..27}
        const int r0 = waveRow + 4 * h;
        float4 kv0 = *(const float4*)(rup + r0);
        float4 kv1 = *(const float4*)(rup + r0 + 8);
        float4 kv2 = *(const float4*)(rup + r0 + 16);
        float4 kv3 = *(const float4*)(rup + r0 + 24);
        float kk[16] = {kv0.x, kv0.y, kv0.z, kv0.w, kv1.x, kv1.y, kv1.z, kv1.w,
                        kv2.x, kv2.y, kv2.z, kv2.w, kv3.x, kv3.y, kv3.z, kv3.w};

#pragma unroll
        for (int i = 0; i < 16; ++i) {
            float sim = acc[i];
            int bin = binOf(sim);
            atomicAdd(&histL[bin * 8 + (sl >> 2)], 1u << (8 * (sl & 3)));
            int grow = waveRow + (i & 3) + 8 * (i >> 2) + 4 * h;
            if (sim > THRV) {
                unsigned slot = atomicAdd(&fnpCnt[sg], 1u);
                if (slot < CF)
                    fnpPack[(size_t)sg * CF + slot] =
                        ((u64)__float_as_uint(sim) << 32) | (u64)(0x3FFFFu - (unsigned)grow);
            }
            float key = kk[i];
            if (key > TAU) {
                unsigned slot = atomicAdd(&negCnt[sg], 1u);
                if (slot < CN)
                    negPack[(size_t)sg * CN + slot] =
                        ((u64)__float_as_uint(key) << 32) |
                        ((u64)(0x3FFFFu - (unsigned)grow) << 9) | (u64)bin;
            }
        }
    }

    __syncthreads();
    // merge u8 histogram to global u32
    for (int q = tid; q < 32 * NB; q += 256) {
        int s2 = q >> 9, bin = q & (NB - 1);
        unsigned c = (histL[bin * 8 + (s2 >> 2)] >> (8 * (s2 & 3))) & 0xFFu;
        if (c) atomicAdd(&hist_g[(size_t)(sbBase + s2) * NB + bin], c);
    }
}

// ---------------------------------------------------------------- kernel C (per-sample finalize)
__global__ __launch_bounds__(256) void k_fin(
    const int* __restrict__ bidx,
    const unsigned* __restrict__ fnpCnt, const unsigned* __restrict__ negCnt,
    const u64* __restrict__ fnpPack, const u64* __restrict__ negPack,
    const unsigned* __restrict__ hist_g, const float* __restrict__ posExp_g,
    const float* __restrict__ f1_g, const float* __restrict__ mem,
    float* __restrict__ losses)
{
    __shared__ u64 arrF[CF];
    __shared__ unsigned khist[1024];
    __shared__ unsigned incl[2512];
    __shared__ u64 bnd[64];
    __shared__ u64 winPk[TOPF];
    __shared__ unsigned exclR[TOPF];
    __shared__ float numW[TOPF];
    __shared__ float f1sh[BITD];
    __shared__ unsigned scr[NB];
    __shared__ unsigned scanBuf[256];
    __shared__ float redF[256];
    __shared__ u64 wmaxS[4];
    __shared__ u64 shBest;
    __shared__ int shI[4];
    __shared__ float shNum;
    __shared__ unsigned bndCnt;

    const int s = blockIdx.x, tid = threadIdx.x;
    const int w = tid >> 6, l = tid & 63;
    const int pos = bidx[s];

    if (tid < 16) *(float4*)&f1sh[tid * 4] = *(const float4*)&f1_g[(size_t)s * BITD + tid * 4];
    if (tid == 0) bndCnt = 0u;
    scr[tid] = hist_g[(size_t)s * NB + tid];
    scr[tid + 256] = hist_g[(size_t)s * NB + tid + 256];
    __syncthreads();

    if (tid == 0) {
        unsigned cum = 0; int beta = NB - 1;
        for (int b2 = 0; b2 < NB; ++b2) {
            cum += scr[b2];
            if (cum >= (unsigned)(RANKA + 1)) { beta = b2; break; }
        }
        shI[0] = beta;
    }

    // ---- fnp top-20 by (sim desc, row asc) via 20 argmax extractions
    unsigned cf = fnpCnt[s]; if (cf > CF) cf = CF;
    for (int i = tid; i < (int)cf; i += 256) arrF[i] = fnpPack[(size_t)s * CF + i];
    __syncthreads();

    for (int wi = 0; wi < TOPF; ++wi) {
        u64 m = 0;
        for (int i = tid; i < (int)cf; i += 256) { u64 v = arrF[i]; m = v > m ? v : m; }
#pragma unroll
        for (int off = 1; off < 64; off <<= 1) { u64 o = __shfl_xor(m, off); m = o > m ? o : m; }
        if (l == 0) wmaxS[w] = m;
        __syncthreads();
        if (tid == 0) {
            u64 best = wmaxS[0];
            if (wmaxS[1] > best) best = wmaxS[1];
            if (wmaxS[2] > best) best = wmaxS[2];
            if (wmaxS[3] > best) best = wmaxS[3];
            winPk[wi] = best; shBest = best;
        }
        __syncthreads();
        u64 best = shBest;
        if (best == 0ull) break;
        for (int i = tid; i < (int)cf; i += 256) if (arrF[i] == best) arrF[i] = 0ull;
        __syncthreads();
    }
    __syncthreads();
    if (tid == 0) {
        int ne = 0;
        for (int wi = 0; wi < TOPF; ++wi) {
            u64 pk = winPk[wi];
            if (pk == 0ull) break;
            unsigned row = 0x3FFFFu - (unsigned)(pk & 0x3FFFFull);
            if ((int)row != pos) exclR[ne++] = row;
        }
        shI[1] = ne;
    }
    __syncthreads();
    const int beta = shI[0], ne = shI[1];

    // e-dots for valid winners (4 lanes per entry)
    {
        int grp = tid >> 2, lp = tid & 3;
        if (grp < ne) {
            unsigned row = exclR[grp];
            const float* mr = mem + (size_t)row * BITD + lp * 16;
            const float* fr = &f1sh[lp * 16];
            float part = 0.f;
#pragma unroll
            for (int m2 = 0; m2 < 16; ++m2) part = fmaf(mr[m2], fr[m2], part);
            part += __shfl_xor(part, 1);
            part += __shfl_xor(part, 2);
            if (lp == 0) {
                float fsim = part * S8T;
                numW[grp] = fsim * expf(fsim);
            }
        }
    }
    __syncthreads();
    if (tid == 0) {
        float numer = posExp_g[s];
        for (int g = 0; g < ne; ++g) numer += numW[g];
        shNum = numer;
    }

    // ---- negatives: top-2500 keys among filtered candidates
    unsigned cn = negCnt[s]; if (cn > CN) cn = CN;
    for (int q = tid; q < 1024; q += 256) khist[q] = 0u;
    __syncthreads();

    // pass A: key histogram of filtered entries
    for (int i = tid; i < (int)cn; i += 256) {
        u64 v = negPack[(size_t)s * CN + i];
        int bin = (int)(v & 511ull);
        if (bin < beta) continue;
        unsigned row = 0x3FFFFu - (unsigned)((v >> 9) & 0x3FFFFull);
        if ((int)row == pos) continue;
        bool ex = false;
        for (int q2 = 0; q2 < ne; ++q2) ex = ex || (exclR[q2] == row);
        if (ex) continue;
        float key = __uint_as_float((unsigned)(v >> 32));
        int kb = (int)((key - TAU) * KHINV);
        kb = kb < 0 ? 0 : (kb > 1023 ? 1023 : kb);
        atomicAdd(&khist[kb], 1u);
    }
    __syncthreads();
    if (tid == 0) {
        unsigned acc2 = 0; int Bs = 0;
        for (int b2 = 1023; b2 >= 0; --b2) {
            unsigned c2 = khist[b2];
            if (acc2 + c2 >= (unsigned)KNEG) { Bs = b2; break; }
            acc2 += c2;
            if (b2 == 0) Bs = 0;
        }
        shI[2] = Bs;
    }
    __syncthreads();
    const int Bstar = shI[2];

    // pass B1: per-thread counts of strictly-above entries
    unsigned cnt = 0;
    for (int i = tid; i < (int)cn; i += 256) {
        u64 v = negPack[(size_t)s * CN + i];
        int bin = (int)(v & 511ull);
        if (bin < beta) continue;
        unsigned row = 0x3FFFFu - (unsigned)((v >> 9) & 0x3FFFFull);
        if ((int)row == pos) continue;
        bool ex = false;
        for (int q2 = 0; q2 < ne; ++q2) ex = ex || (exclR[q2] == row);
        if (ex) continue;
        float key = __uint_as_float((unsigned)(v >> 32));
        int kb = (int)((key - TAU) * KHINV);
        kb = kb < 0 ? 0 : (kb > 1023 ? 1023 : kb);
        if (kb > Bstar) cnt++;
    }
    scanBuf[tid] = cnt;
    __syncthreads();
    if (tid == 0) {
        unsigned run = 0;
        for (int q2 = 0; q2 < 256; ++q2) { unsigned t3 = scanBuf[q2]; scanBuf[q2] = run; run += t3; }
        shI[3] = (int)run;   // C1tot
    }
    __syncthreads();

    // pass B2: place above-entries (deterministic), gather boundary-bin entries
    {
        unsigned off2 = scanBuf[tid];
        for (int i = tid; i < (int)cn; i += 256) {
            u64 v = negPack[(size_t)s * CN + i];
            int bin = (int)(v & 511ull);
            if (bin < beta) continue;
            unsigned row = 0x3FFFFu - (unsigned)((v >> 9) & 0x3FFFFull);
            if ((int)row == pos) continue;
            bool ex = false;
            for (int q2 = 0; q2 < ne; ++q2) ex = ex || (exclR[q2] == row);
            if (ex) continue;
            float key = __uint_as_float((unsigned)(v >> 32));
            int kb = (int)((key - TAU) * KHINV);
            kb = kb < 0 ? 0 : (kb > 1023 ? 1023 : kb);
            if (kb > Bstar) {
                incl[off2++] = row;
            } else if (kb == Bstar) {
                unsigned sl2 = atomicAdd(&bndCnt, 1u);
                if (sl2 < 64u) bnd[sl2] = v;
            }
        }
    }
    __syncthreads();
    if (tid == 0) {
        int C1 = shI[3];
        int m = KNEG - C1;
        int bc = (int)bndCnt; if (bc > 64) bc = 64;
        if (m > bc) m = bc;
        if (m < 0) m = 0;
        for (int t2 = 0; t2 < m; ++t2) {          // exact top-m of boundary bin
            u64 best = 0; int bi = -1;
            for (int q2 = 0; q2 < bc; ++q2)
                if (bnd[q2] > best) { best = bnd[q2]; bi = q2; }
            incl[C1 + t2] = 0x3FFFFu - (unsigned)((best >> 9) & 0x3FFFFull);
            bnd[bi] = 0;
        }
        shI[3] = C1 + m;   // nInc
    }
    __syncthreads();
    const int nInc = shI[3];

    // denominator: e-dots over included rows (4 lanes per entry)
    float dpart = 0.f;
    {
        int grp = tid >> 2, lp = tid & 3;
        float f1r[16];
#pragma unroll
        for (int m2 = 0; m2 < 16; ++m2) f1r[m2] = f1sh[lp * 16 + m2];
        for (int e2 = grp; e2 < nInc; e2 += 64) {
            unsigned row = incl[e2];
            const float* mr = mem + (size_t)row * BITD + lp * 16;
            float part = 0.f;
#pragma unroll
            for (int m2 = 0; m2 < 16; ++m2) part = fmaf(mr[m2], f1r[m2], part);
            part += __shfl_xor(part, 1);
            part += __shfl_xor(part, 2);
            if (lp == 0) dpart += expf(part * S8T);
        }
    }
    redF[tid] = dpart;
    __syncthreads();
    for (int st = 128; st > 0; st >>= 1) {
        if (tid < st) redF[tid] += redF[tid + st];
        __syncthreads();
    }
    if (tid == 0) {
        float D = redF[0] + posExp_g[s];
        losses[s] = -logf(shNum / D) / (1.0f + (float)ne);
    }
}

// ---------------------------------------------------------------- small kernels
__global__ __launch_bounds__(256) void k_loss(const float* __restrict__ losses,
                                              float* __restrict__ out)
{
    __shared__ float buf[256];
    int t = threadIdx.x;
    buf[t] = losses[t];
    __syncthreads();
    for (int st = 128; st > 0; st >>= 1) {
        if (t < st) buf[t] += buf[t + st];
        __syncthreads();
    }
    if (t == 0) out[0] = buf[0] / 256.0f;
}

__global__ __launch_bounds__(256) void k_copy(const float* __restrict__ mem,
                                              float* __restrict__ out)
{
    size_t i = ((size_t)blockIdx.x * 256 + threadIdx.x) * 4;
    if (i < (size_t)NDATA * BITD) {
        float4 v = *(const float4*)&mem[i];
        out[1 + i] = v.x; out[2 + i] = v.y; out[3 + i] = v.z; out[4 + i] = v.w;
    }
}

__global__ __launch_bounds__(64) void k_scatter(const int* __restrict__ bidx,
                                                const float* __restrict__ upd,
                                                float* __restrict__ out)
{
    int s = blockIdx.x, j = threadIdx.x;
    int pos = bidx[s];
    bool last = true;
    for (int s2 = s + 1; s2 < BATCH; ++s2)
        if (bidx[s2] == pos) last = false;   // last write wins (np semantics)
    if (last) out[1 + (size_t)pos * BITD + j] = upd[s * BITD + j];
}

// ---------------------------------------------------------------- launcher
extern "C" void kernel_launch(void* const* d_in, const int* in_sizes, int n_in,
                              void* d_out, int out_size, void* d_ws, size_t ws_size,
                              hipStream_t stream)
{
    const float* iA = (const float*)d_in[0];
    const float* iB = (const float*)d_in[1];
    const float* tA = (const float*)d_in[2];
    const float* tB = (const float*)d_in[3];
    const float* mem = (const float*)d_in[4];
    const float* ru  = (const float*)d_in[5];
    const int* bidx  = (const int*)d_in[6];
    float* out = (float*)d_out;

    char* w = (char*)d_ws;
    u64* fnpPack = (u64*)w;          w += (size_t)BATCH * CF * 8;      // 4 MB
    u64* negPack = (u64*)w;          w += (size_t)BATCH * CN * 8;      // 12.6 MB
    float* f1_g = (float*)w;         w += BATCH * BITD * 4;
    float* upd_g = (float*)w;        w += BATCH * BITD * 4;
    float* posExp_g = (float*)w;     w += BATCH * 4;
    float* losses = (float*)w;       w += BATCH * 4;
    unsigned* fnpCnt = (unsigned*)w; w += BATCH * 4;
    unsigned* negCnt = (unsigned*)w; w += BATCH * 4;
    unsigned* hist_g = (unsigned*)w; w += (size_t)BATCH * NB * 4;      // 512 KB
    unsigned short* fsumHi = (unsigned short*)w; w += BATCH * BITD * 2;
    unsigned short* fsumLo = (unsigned short*)w; w += BATCH * BITD * 2;

    k_prep<<<BATCH, 64, 0, stream>>>(iA, iB, tA, tB, mem, bidx, fsumHi, fsumLo,
                                     f1_g, upd_g, posExp_g, fnpCnt, negCnt, hist_g);
    k_copy<<<(NDATA * BITD) / 4 / 256, 256, 0, stream>>>(mem, out);
    k_main<<<dim3(NCH, NSB), 256, 0, stream>>>(mem, ru, fsumHi, fsumLo,
                                               fnpCnt, negCnt, fnpPack, negPack, hist_g);
    k_fin<<<BATCH, 256, 0, stream>>>(bidx, fnpCnt, negCnt, fnpPack, negPack,
                                     hist_g, posExp_g, f1_g, mem, losses);
    k_loss<<<1, 256, 0, stream>>>(losses, out);
    k_scatter<<<BATCH, 64, 0, stream>>>(bidx, upd_g, out);
}